// Round 1
// baseline (798.695 us; speedup 1.0000x reference)
//
#include <hip/hip_runtime.h>
#include <hip/hip_bf16.h>

// Restriction: h_coarse = R @ x_fine, R in COO (rows, cols, vals).
// Strategy (round 0): atomic scatter. 32 lanes per edge, float4 gather
// (512 B coalesced per fine-node row), 4 hardware f32 atomics per lane.

__global__ __launch_bounds__(256) void restriction_scatter(
    const float* __restrict__ x_fine,
    const float* __restrict__ r_vals,
    const int*   __restrict__ r_rows,
    const int*   __restrict__ r_cols,
    float*       __restrict__ out,
    int nnz)
{
    int tid = blockIdx.x * blockDim.x + threadIdx.x;
    int e = tid >> 5;        // edge index: 32 threads per edge
    int q = tid & 31;        // each thread owns features [4q, 4q+4)
    if (e >= nnz) return;

    int   row = r_rows[e];
    int   col = r_cols[e];
    float val = r_vals[e];

    const float4* xf = reinterpret_cast<const float4*>(x_fine + (size_t)col * 128);
    float4 v = xf[q];

    float* o = out + (size_t)row * 128 + q * 4;
    // unsafeAtomicAdd -> global_atomic_add_f32 (no CAS loop).
    unsafeAtomicAdd(o + 0, v.x * val);
    unsafeAtomicAdd(o + 1, v.y * val);
    unsafeAtomicAdd(o + 2, v.z * val);
    unsafeAtomicAdd(o + 3, v.w * val);
}

extern "C" void kernel_launch(void* const* d_in, const int* in_sizes, int n_in,
                              void* d_out, int out_size, void* d_ws, size_t ws_size,
                              hipStream_t stream) {
    const float* x_fine = (const float*)d_in[0];
    const float* r_vals = (const float*)d_in[1];
    const int*   r_rows = (const int*)d_in[2];
    const int*   r_cols = (const int*)d_in[3];
    float* out = (float*)d_out;

    int nnz = in_sizes[1];

    // d_out is poisoned 0xAA before every timed launch — zero it first.
    hipMemsetAsync(d_out, 0, (size_t)out_size * sizeof(float), stream);

    int threads_total = nnz * 32;
    int blocks = (threads_total + 255) / 256;
    hipLaunchKernelGGL(restriction_scatter, dim3(blocks), dim3(256), 0, stream,
                       x_fine, r_vals, r_rows, r_cols, out, nnz);
}

// Round 3
// 319.660 us; speedup vs baseline: 2.4986x; 2.4986x over previous
//
#include <hip/hip_runtime.h>
#include <hip/hip_bf16.h>

// Restriction: h_coarse = R @ x_fine, R in COO (rows, cols, vals).
// Round 2 (resubmit — round 2 bench hit GPUAcquisitionTimeout, never ran):
// device-built CSR + register aggregation.
//   1. histogram rows (400K int atomics)
//   2. exclusive scan of row counts (single 1024-thread block)
//   3. scatter packed {col, val} into CSR order (400K int atomics)
//   4. one wave per coarse row: gather + FMA in registers, ONE write per row
// Replaces 51.2M f32 atomics (819 MB write-through, round-1 bottleneck)
// with 0.8M int atomics + 28.8 MB plain writes.
// Workspace use: (3*50000+2)*4 B + 400000*8 B ~= 3.8 MB.

#define F 128

__global__ __launch_bounds__(256) void hist_kernel(
    const int* __restrict__ rows, int* __restrict__ counts, int nnz)
{
    int i = blockIdx.x * blockDim.x + threadIdx.x;
    if (i < nnz) atomicAdd(&counts[rows[i]], 1);
}

// Single-workgroup exclusive scan: thread t owns a contiguous chunk.
__global__ __launch_bounds__(1024) void scan_kernel(
    const int* __restrict__ counts, int* __restrict__ offsets, int n)
{
    __shared__ int sums[1024];
    int t = threadIdx.x;
    int chunk = (n + 1023) / 1024;
    int beg = t * chunk;
    int end = min(beg + chunk, n);
    int s = 0;
    for (int i = beg; i < end; ++i) s += counts[i];
    sums[t] = s;
    __syncthreads();
    // Hillis-Steele inclusive scan over per-thread sums.
    for (int off = 1; off < 1024; off <<= 1) {
        int v = (t >= off) ? sums[t - off] : 0;
        __syncthreads();
        sums[t] += v;
        __syncthreads();
    }
    int run = (t == 0) ? 0 : sums[t - 1];   // exclusive prefix for this chunk
    for (int i = beg; i < end; ++i) { offsets[i] = run; run += counts[i]; }
    if (t == 1023) offsets[n] = run;        // total nnz (works even if chunk empty)
}

__global__ __launch_bounds__(256) void scatter_kernel(
    const int* __restrict__ rows, const int* __restrict__ cols,
    const float* __restrict__ vals, const int* __restrict__ offsets,
    int* __restrict__ cursor, int2* __restrict__ edges, int nnz)
{
    int i = blockIdx.x * blockDim.x + threadIdx.x;
    if (i < nnz) {
        int r = rows[i];
        int pos = offsets[r] + atomicAdd(&cursor[r], 1);
        edges[pos] = make_int2(cols[i], __float_as_int(vals[i]));
    }
}

// One 64-lane wave per coarse row; each lane owns 2 features (float2).
__global__ __launch_bounds__(256) void gather_rows(
    const float* __restrict__ x_fine, const int2* __restrict__ edges,
    const int* __restrict__ offsets, float* __restrict__ out, int n_rows)
{
    int gid = blockIdx.x * blockDim.x + threadIdx.x;
    int row = gid >> 6;
    int lane = gid & 63;
    if (row >= n_rows) return;

    int beg = offsets[row];
    int end = offsets[row + 1];
    float2 acc = make_float2(0.f, 0.f);
    for (int i = beg; i < end; ++i) {
        int2  e   = edges[i];                 // wave-uniform load
        float val = __int_as_float(e.y);
        float2 v  = reinterpret_cast<const float2*>(
                        x_fine + (size_t)e.x * F)[lane];  // coalesced 512 B/wave
        acc.x += val * v.x;
        acc.y += val * v.y;
    }
    reinterpret_cast<float2*>(out + (size_t)row * F)[lane] = acc;
}

extern "C" void kernel_launch(void* const* d_in, const int* in_sizes, int n_in,
                              void* d_out, int out_size, void* d_ws, size_t ws_size,
                              hipStream_t stream) {
    const float* x_fine = (const float*)d_in[0];
    const float* r_vals = (const float*)d_in[1];
    const int*   r_rows = (const int*)d_in[2];
    const int*   r_cols = (const int*)d_in[3];
    float* out = (float*)d_out;

    int nnz    = in_sizes[1];
    int n_rows = out_size / F;

    // Workspace layout (ints):
    //   [0, R)        counts   (zeroed)
    //   [R, 2R)       cursor   (zeroed)
    //   [2R, 3R+1]    offsets
    //   [3R+2, ...)   edges (int2, 8-byte aligned)
    int* ws_i    = (int*)d_ws;
    int* counts  = ws_i;
    int* cursor  = ws_i + n_rows;
    int* offsets = ws_i + 2 * (size_t)n_rows;
    int2* edges  = (int2*)(ws_i + 3 * (size_t)n_rows + 2);

    // ws is poisoned 0xAA before every timed launch — zero counts+cursor.
    hipMemsetAsync(counts, 0, 2 * (size_t)n_rows * sizeof(int), stream);

    int b_nnz = (nnz + 255) / 256;
    hipLaunchKernelGGL(hist_kernel, dim3(b_nnz), dim3(256), 0, stream,
                       r_rows, counts, nnz);
    hipLaunchKernelGGL(scan_kernel, dim3(1), dim3(1024), 0, stream,
                       counts, offsets, n_rows);
    hipLaunchKernelGGL(scatter_kernel, dim3(b_nnz), dim3(256), 0, stream,
                       r_rows, r_cols, r_vals, offsets, cursor, edges, nnz);

    int b_rows = ((size_t)n_rows * 64 + 255) / 256;
    hipLaunchKernelGGL(gather_rows, dim3(b_rows), dim3(256), 0, stream,
                       x_fine, edges, offsets, out, n_rows);
}

// Round 4
// 206.266 us; speedup vs baseline: 3.8722x; 1.5497x over previous
//
#include <hip/hip_runtime.h>
#include <hip/hip_bf16.h>

// Restriction: h_coarse = R @ x_fine, R in COO (rows, cols, vals).
// Round 4: fixed-capacity bins (kills hist+scan) + MLP-4 gather.
//   1. scatter_bins: pos=atomicAdd(count[row]); pos<CAP -> bins[row*CAP+pos],
//      else exact overflow list (P(deg>32|lambda=8) ~ 1e-12).
//   2. gather_rows: wave/row. Lanes<deg preload edges in ONE coalesced 256B
//      load, __shfl-broadcast, process 4 edges/iter -> 4 independent 512B
//      x_fine loads in flight (round-3 gather was MLP~1, 20% BW).
//   3. ovf_apply: atomic fallback for overflow edges (normally 0 work).
// ws: counts 200KB + ovfcnt 16B + ovf 4.8MB + bins cap*50K*8 (12.8MB @cap=32).
// cap adapts down if ws_size is small; cap=0 degenerates to all-atomic (exact).

#define F 128

__global__ __launch_bounds__(256) void scatter_bins(
    const int*   __restrict__ rows, const int* __restrict__ cols,
    const float* __restrict__ vals,
    int* __restrict__ counts, int2* __restrict__ bins, int cap,
    int* __restrict__ ovf_cnt, int3* __restrict__ ovf, int nnz)
{
    int i = blockIdx.x * blockDim.x + threadIdx.x;
    if (i >= nnz) return;
    int r = rows[i];
    int pos = atomicAdd(&counts[r], 1);
    if (pos < cap) {
        bins[(size_t)r * cap + pos] = make_int2(cols[i], __float_as_int(vals[i]));
    } else {
        int p = atomicAdd(ovf_cnt, 1);
        ovf[p] = make_int3(r, cols[i], __float_as_int(vals[i]));
    }
}

// One 64-lane wave per coarse row; lane owns 2 features (float2).
// Edges preloaded into registers (lanes 0..deg-1), processed 4 at a time.
__global__ __launch_bounds__(256) void gather_rows(
    const float* __restrict__ x_fine, const int2* __restrict__ bins,
    const int* __restrict__ counts, float* __restrict__ out,
    int n_rows, int cap)
{
    int gid  = blockIdx.x * blockDim.x + threadIdx.x;
    int row  = gid >> 6;
    int lane = gid & 63;
    if (row >= n_rows) return;

    int deg = counts[row];
    if (deg > cap) deg = cap;

    // One coalesced 256B edge load per row; zero-pad in registers so the
    // group-of-4 loop below is blind-safe (pad edges: col=0, val=0).
    int2 e = make_int2(0, 0);
    if (lane < deg) e = bins[(size_t)row * cap + lane];

    const float2* xf = reinterpret_cast<const float2*>(x_fine);
    float2 acc = make_float2(0.f, 0.f);
    int deg4 = (deg + 3) & ~3;

    for (int j = 0; j < deg4; j += 4) {
        int c0 = __shfl(e.x, j + 0), c1 = __shfl(e.x, j + 1);
        int c2 = __shfl(e.x, j + 2), c3 = __shfl(e.x, j + 3);
        float w0 = __int_as_float(__shfl(e.y, j + 0));
        float w1 = __int_as_float(__shfl(e.y, j + 1));
        float w2 = __int_as_float(__shfl(e.y, j + 2));
        float w3 = __int_as_float(__shfl(e.y, j + 3));
        // 4 independent 512B/wave loads -> MLP 4.
        float2 a = xf[(size_t)c0 * 64 + lane];
        float2 b = xf[(size_t)c1 * 64 + lane];
        float2 c = xf[(size_t)c2 * 64 + lane];
        float2 d = xf[(size_t)c3 * 64 + lane];
        acc.x += w0 * a.x; acc.y += w0 * a.y;
        acc.x += w1 * b.x; acc.y += w1 * b.y;
        acc.x += w2 * c.x; acc.y += w2 * c.y;
        acc.x += w3 * d.x; acc.y += w3 * d.y;
    }
    reinterpret_cast<float2*>(out)[(size_t)row * 64 + lane] = acc;
}

// Exact fallback for overflow edges (normally ovf_cnt == 0).
__global__ __launch_bounds__(256) void ovf_apply(
    const float* __restrict__ x_fine, const int3* __restrict__ ovf,
    const int* __restrict__ ovf_cnt, float* __restrict__ out)
{
    int n = *ovf_cnt;
    int total = n * 32;
    for (int idx = blockIdx.x * blockDim.x + threadIdx.x; idx < total;
         idx += gridDim.x * blockDim.x) {
        int e = idx >> 5, q = idx & 31;
        int3 t = ovf[e];
        float val = __int_as_float(t.z);
        float4 v = reinterpret_cast<const float4*>(x_fine + (size_t)t.y * F)[q];
        float* o = out + (size_t)t.x * F + q * 4;
        unsafeAtomicAdd(o + 0, v.x * val);
        unsafeAtomicAdd(o + 1, v.y * val);
        unsafeAtomicAdd(o + 2, v.z * val);
        unsafeAtomicAdd(o + 3, v.w * val);
    }
}

extern "C" void kernel_launch(void* const* d_in, const int* in_sizes, int n_in,
                              void* d_out, int out_size, void* d_ws, size_t ws_size,
                              hipStream_t stream) {
    const float* x_fine = (const float*)d_in[0];
    const float* r_vals = (const float*)d_in[1];
    const int*   r_rows = (const int*)d_in[2];
    const int*   r_cols = (const int*)d_in[3];
    float* out = (float*)d_out;

    int nnz    = in_sizes[1];
    int n_rows = out_size / F;

    // Workspace layout (byte offsets):
    //   0                : counts   (n_rows int, zeroed)
    //   counts_b         : ovf_cnt  (1 int, zeroed; padded to 16B)
    //   counts_b+16      : ovf      (nnz int3 = 12B each)
    //   counts_b+16+ovf_b: bins     (n_rows*cap int2)
    size_t counts_b = (size_t)n_rows * 4;
    size_t ovf_b    = (size_t)nnz * 12;
    size_t fixed    = counts_b + 16 + ovf_b;

    char* ws = (char*)d_ws;
    int*  counts  = (int*)ws;
    int*  ovf_cnt = (int*)(ws + counts_b);
    int3* ovf     = (int3*)(ws + counts_b + 16);
    int2* bins    = (int2*)(ws + fixed);

    int cap = 0;
    if (ws_size > fixed) {
        size_t c = (ws_size - fixed) / ((size_t)n_rows * 8);
        cap = (int)(c > 32 ? 32 : c);
    }
    cap &= ~3;   // multiple of 4 for the blind group-of-4 loop

    // counts + ovf_cnt are contiguous; ws is poisoned 0xAA before each call.
    hipMemsetAsync(counts, 0, counts_b + 16, stream);

    int b_nnz = (nnz + 255) / 256;
    hipLaunchKernelGGL(scatter_bins, dim3(b_nnz), dim3(256), 0, stream,
                       r_rows, r_cols, r_vals, counts, bins, cap,
                       ovf_cnt, ovf, nnz);

    int b_rows = (int)(((size_t)n_rows * 64 + 255) / 256);
    hipLaunchKernelGGL(gather_rows, dim3(b_rows), dim3(256), 0, stream,
                       x_fine, bins, counts, out, n_rows, cap);

    hipLaunchKernelGGL(ovf_apply, dim3(256), dim3(256), 0, stream,
                       x_fine, ovf, ovf_cnt, out);
}

// Round 7
// 202.458 us; speedup vs baseline: 3.9450x; 1.0188x over previous
//
#include <hip/hip_runtime.h>
#include <hip/hip_bf16.h>

// Restriction: h_coarse = R @ x_fine, R in COO (rows, cols, vals).
// Round 5 (2nd resubmit — rounds 5 and 6 both hit GPUAcquisitionTimeout):
// cap=16 bins (L2-resident 6.4MB) + MLP-8 gather.
//   1. scatter_bins: pos=atomicAdd(count[row]); pos<16 -> bins[row*16+pos],
//      else exact overflow list (P(deg>16|lambda=8)~3.7e-3 -> ~600 edges).
//   2. gather_rows: wave/row. Lanes<deg preload edges (one coalesced load),
//      __shfl-broadcast, 8 independent 512B x_fine loads in flight per iter.
//      Zero-padded edges (col=0,val=0) make the blind 8-group exact; padding
//      loads hit the L1-hot row 0.
//   3. ovf_apply: exact atomic fallback for overflow edges (~600).
// Fixed floor: harness re-poison of ~400MB ws (observed 61.6us fill) + d_in
// restore is inside dur_us; our dispatches are the remaining ~115us target.

#define F   128
#define CAP 16

__global__ __launch_bounds__(256) void scatter_bins(
    const int*   __restrict__ rows, const int* __restrict__ cols,
    const float* __restrict__ vals,
    int* __restrict__ counts, int2* __restrict__ bins,
    int* __restrict__ ovf_cnt, int3* __restrict__ ovf, int nnz)
{
    int i = blockIdx.x * blockDim.x + threadIdx.x;
    if (i >= nnz) return;
    // Streaming reads (no reuse) — keep them out of L2's way.
    int   r = __builtin_nontemporal_load(rows + i);
    int   c = __builtin_nontemporal_load(cols + i);
    float v = __builtin_nontemporal_load(vals + i);
    int pos = atomicAdd(&counts[r], 1);
    if (pos < CAP) {
        bins[(size_t)r * CAP + pos] = make_int2(c, __float_as_int(v));
    } else {
        int p = atomicAdd(ovf_cnt, 1);
        ovf[p] = make_int3(r, c, __float_as_int(v));
    }
}

// One 64-lane wave per coarse row; lane owns 2 features (float2).
// Edges preloaded into registers (lanes 0..deg-1), processed 8 at a time.
__global__ __launch_bounds__(256) void gather_rows(
    const float* __restrict__ x_fine, const int2* __restrict__ bins,
    const int* __restrict__ counts, float* __restrict__ out, int n_rows)
{
    int gid  = blockIdx.x * blockDim.x + threadIdx.x;
    int row  = gid >> 6;
    int lane = gid & 63;
    if (row >= n_rows) return;

    int deg = counts[row];
    if (deg > CAP) deg = CAP;

    // One coalesced 128B edge load per row; zero-pad in registers so the
    // blind group-of-8 loop is exact (pad: col=0, val=0 -> adds 0*row0).
    int2 e = make_int2(0, 0);
    if (lane < deg) e = bins[(size_t)row * CAP + lane];

    const float2* xf = reinterpret_cast<const float2*>(x_fine);
    float2 acc = make_float2(0.f, 0.f);
    int deg8 = (deg + 7) & ~7;

    for (int j = 0; j < deg8; j += 8) {
        int   cc[8];
        float ww[8];
#pragma unroll
        for (int k = 0; k < 8; ++k) {
            cc[k] = __shfl(e.x, j + k);
            ww[k] = __int_as_float(__shfl(e.y, j + k));
        }
        float2 vv[8];
#pragma unroll
        for (int k = 0; k < 8; ++k)      // 8 independent 512B/wave loads
            vv[k] = xf[(size_t)cc[k] * 64 + lane];
#pragma unroll
        for (int k = 0; k < 8; ++k) {
            acc.x += ww[k] * vv[k].x;
            acc.y += ww[k] * vv[k].y;
        }
    }
    reinterpret_cast<float2*>(out)[(size_t)row * 64 + lane] = acc;
}

// Exact fallback for overflow edges (~600 expected at CAP=16).
__global__ __launch_bounds__(256) void ovf_apply(
    const float* __restrict__ x_fine, const int3* __restrict__ ovf,
    const int* __restrict__ ovf_cnt, float* __restrict__ out)
{
    int n = *ovf_cnt;
    int total = n * 32;
    for (int idx = blockIdx.x * blockDim.x + threadIdx.x; idx < total;
         idx += gridDim.x * blockDim.x) {
        int e = idx >> 5, q = idx & 31;
        int3 t = ovf[e];
        float val = __int_as_float(t.z);
        float4 v = reinterpret_cast<const float4*>(x_fine + (size_t)t.y * F)[q];
        float* o = out + (size_t)t.x * F + q * 4;
        unsafeAtomicAdd(o + 0, v.x * val);
        unsafeAtomicAdd(o + 1, v.y * val);
        unsafeAtomicAdd(o + 2, v.z * val);
        unsafeAtomicAdd(o + 3, v.w * val);
    }
}

extern "C" void kernel_launch(void* const* d_in, const int* in_sizes, int n_in,
                              void* d_out, int out_size, void* d_ws, size_t ws_size,
                              hipStream_t stream) {
    const float* x_fine = (const float*)d_in[0];
    const float* r_vals = (const float*)d_in[1];
    const int*   r_rows = (const int*)d_in[2];
    const int*   r_cols = (const int*)d_in[3];
    float* out = (float*)d_out;

    int nnz    = in_sizes[1];
    int n_rows = out_size / F;

    // Workspace layout (byte offsets):
    //   0                : counts   (n_rows int, zeroed)
    //   counts_b         : ovf_cnt  (1 int, zeroed; padded to 16B)
    //   counts_b+16      : ovf      (nnz int3 = 12B each)
    //   counts_b+16+ovf_b: bins     (n_rows*CAP int2 = 6.4MB)
    size_t counts_b = (size_t)n_rows * 4;
    size_t ovf_b    = (size_t)nnz * 12;
    size_t fixed    = counts_b + 16 + ovf_b;

    char* ws = (char*)d_ws;
    int*  counts  = (int*)ws;
    int*  ovf_cnt = (int*)(ws + counts_b);
    int3* ovf     = (int3*)(ws + counts_b + 16);
    int2* bins    = (int2*)(ws + fixed);

    // counts + ovf_cnt contiguous; ws is poisoned 0xAA before each call.
    hipMemsetAsync(counts, 0, counts_b + 16, stream);

    int b_nnz = (nnz + 255) / 256;
    hipLaunchKernelGGL(scatter_bins, dim3(b_nnz), dim3(256), 0, stream,
                       r_rows, r_cols, r_vals, counts, bins,
                       ovf_cnt, ovf, nnz);

    int b_rows = (int)(((size_t)n_rows * 64 + 255) / 256);
    hipLaunchKernelGGL(gather_rows, dim3(b_rows), dim3(256), 0, stream,
                       x_fine, bins, counts, out, n_rows);

    hipLaunchKernelGGL(ovf_apply, dim3(64), dim3(256), 0, stream,
                       x_fine, ovf, ovf_cnt, out);
}